// Round 1
// baseline (9772.803 us; speedup 1.0000x reference)
//
#include <hip/hip_runtime.h>
#include <stdint.h>

typedef unsigned short u16;
typedef unsigned int u32;

#define B_ 64
#define T_ 512
#define N_ 128
#define H_ 512
#define NWG 64
#define KDIM 640      // H + N
#define PITCH 648     // KDIM + 8 bf16 pad -> LDS row stride 1296B (2-way bank alias = free)
#define GLP 33        // gate LDS pitch (fp32)

typedef __attribute__((ext_vector_type(8))) short short8;
typedef __attribute__((ext_vector_type(4))) float floatx4;

__device__ __forceinline__ float sigf(float x) { return 1.0f / (1.0f + __expf(-x)); }
__device__ __forceinline__ float tanh_(float x) { return 1.0f - 2.0f / (1.0f + __expf(2.0f * x)); }

__device__ __forceinline__ u16 f2bf(float x) {
    u32 u = __float_as_uint(x);
    u32 r = (u + 0x7FFFu + ((u >> 16) & 1u)) >> 16;   // RNE
    return (u16)r;
}

// X [B,T,N] fp32 -> Xb [T,B,N] bf16 (time-major so each step's x is contiguous)
__global__ __launch_bounds__(256) void k_xb(const float* __restrict__ X, u16* __restrict__ Xb) {
    int i = blockIdx.x * 256 + threadIdx.x;     // i = t*8192 + b*128 + n
    int n = i & 127, b = (i >> 7) & 63, t = i >> 13;
    Xb[i] = f2bf(X[(b * T_ + t) * N_ + n]);
}

// Wcat^T [2048 cols][640 k] bf16: rows k<512 from Wh, k>=512 from Wx
__global__ __launch_bounds__(256) void k_wcat(const float* __restrict__ Wx, const float* __restrict__ Wh,
                                              u16* __restrict__ Wt) {
    int i = blockIdx.x * 256 + threadIdx.x;     // i = k*2048 + c  (coalesced reads)
    int c = i & 2047, k = i >> 11;
    float v = (k < H_) ? Wh[k * 2048 + c] : Wx[(k - H_) * 2048 + c];
    Wt[c * KDIM + k] = f2bf(v);
}

// Persistent cooperative LSTM. WG w owns h-indices [8w, 8w+8) -> 32 gate cols.
// hs: [513][64][512] bf16 rolling h buffer; step t reads hs[t], writes hs[t+1].
__global__ __launch_bounds__(256, 1) void k_lstm(const u16* __restrict__ Wt, const u16* __restrict__ Xb,
                                                 u16* __restrict__ hs, const float* __restrict__ bias,
                                                 u32* __restrict__ cnt) {
    __shared__ u16 sInp[64 * PITCH];   // [h | x] staged per step, 82944B
    __shared__ u16 sW[32 * PITCH];     // weight slice, resident all 512 steps, 41472B
    __shared__ float sG[64 * GLP];     // gate outputs, 8448B
    __shared__ float sB[32];

    const int tid = threadIdx.x;
    const int w = blockIdx.x;
    const int lane = tid & 63, wv = tid >> 6;
    const int l16 = lane & 15, quad = lane >> 4;

    // one-time: weight slice -> LDS. local col lc = g*8 + jj -> global col g*512 + w*8 + jj
    for (int u = tid; u < 32 * 80; u += 256) {
        int lc = u / 80, ch = u - lc * 80;
        int gc = (lc >> 3) * H_ + w * 8 + (lc & 7);
        short8 v = *(const short8*)(Wt + (size_t)gc * KDIM + ch * 8);
        *(short8*)(sW + lc * PITCH + ch * 8) = v;
    }
    if (tid < 32) {
        int gc = (tid >> 3) * H_ + w * 8 + (tid & 7);
        sB[tid] = bias[gc] + (((tid >> 3) == 2) ? 1.0f : 0.0f);   // fold forget_bias into f
    }

    // gate-math mapping: thread owns (b, jj0) and (b, jj0+1); c persists in regs
    const int gb = tid >> 2;
    const int jj0 = (tid & 3) * 2;
    float c0 = 0.f, c1 = 0.f;

    for (int t = 0; t < T_; ++t) {
        // stage h_t (all 64x512) and x_t (64x128) into sInp
        const u16* hsrc = hs + (size_t)t * (64 * H_);
        for (int u = tid; u < 4096; u += 256) {
            int b = u >> 6, ch = u & 63;
            short8 v = *(const short8*)(hsrc + b * H_ + ch * 8);
            *(short8*)(sInp + b * PITCH + ch * 8) = v;
        }
        const u16* xsrc = Xb + (size_t)t * (64 * N_);
        for (int u = tid; u < 1024; u += 256) {
            int b = u >> 4, ch = u & 15;
            short8 v = *(const short8*)(xsrc + b * N_ + ch * 8);
            *(short8*)(sInp + b * PITCH + H_ + ch * 8) = v;
        }
        __syncthreads();

        // wave wv: M-tile = batches [16wv,16wv+16), N-tiles: cols 0..15 (i,j), 16..31 (f,o)
        floatx4 acc0 = {0.f, 0.f, 0.f, 0.f}, acc1 = {0.f, 0.f, 0.f, 0.f};
        const u16* arow  = sInp + (16 * wv + l16) * PITCH + quad * 8;
        const u16* brow0 = sW + l16 * PITCH + quad * 8;
        const u16* brow1 = sW + (16 + l16) * PITCH + quad * 8;
#pragma unroll
        for (int ks = 0; ks < KDIM / 32; ++ks) {
            short8 a  = *(const short8*)(arow + ks * 32);
            short8 b0 = *(const short8*)(brow0 + ks * 32);
            short8 b1 = *(const short8*)(brow1 + ks * 32);
            acc0 = __builtin_amdgcn_mfma_f32_16x16x32_bf16(a, b0, acc0, 0, 0, 0);
            acc1 = __builtin_amdgcn_mfma_f32_16x16x32_bf16(a, b1, acc1, 0, 0, 0);
        }
        // C/D layout: col = lane&15, row = quad*4 + reg  (m89-verified)
        int gbr = 16 * wv + quad * 4;
#pragma unroll
        for (int r = 0; r < 4; ++r) {
            sG[(gbr + r) * GLP + l16]      = acc0[r];
            sG[(gbr + r) * GLP + 16 + l16] = acc1[r];
        }
        __syncthreads();

        // gate math: cols [i0..7 | j0..7 | f0..7 | o0..7]
        float iv0 = sG[gb * GLP + jj0]          + sB[jj0];
        float iv1 = sG[gb * GLP + jj0 + 1]      + sB[jj0 + 1];
        float jv0 = sG[gb * GLP + 8 + jj0]      + sB[8 + jj0];
        float jv1 = sG[gb * GLP + 8 + jj0 + 1]  + sB[8 + jj0 + 1];
        float fv0 = sG[gb * GLP + 16 + jj0]     + sB[16 + jj0];
        float fv1 = sG[gb * GLP + 16 + jj0 + 1] + sB[16 + jj0 + 1];
        float ov0 = sG[gb * GLP + 24 + jj0]     + sB[24 + jj0];
        float ov1 = sG[gb * GLP + 24 + jj0 + 1] + sB[24 + jj0 + 1];

        c0 = sigf(fv0) * c0 + sigf(iv0) * tanh_(jv0);
        c1 = sigf(fv1) * c1 + sigf(iv1) * tanh_(jv1);
        float h0 = sigf(ov0) * tanh_(c0);
        float h1 = sigf(ov1) * tanh_(c1);
        u32 packed = ((u32)f2bf(h1) << 16) | (u32)f2bf(h0);
        *(u32*)(hs + (size_t)(t + 1) * (64 * H_) + gb * H_ + w * 8 + jj0) = packed;

        // release writes, then monotone-counter grid barrier (deadlock-free; guarded)
        __threadfence();
        __syncthreads();
        if (tid == 0) {
            __hip_atomic_fetch_add(cnt, 1u, __ATOMIC_RELEASE, __HIP_MEMORY_SCOPE_AGENT);
            u32 target = (u32)(t + 1) * NWG;
            int guard = 0;
            while (__hip_atomic_load(cnt, __ATOMIC_ACQUIRE, __HIP_MEMORY_SCOPE_AGENT) < target) {
                __builtin_amdgcn_s_sleep(1);
                if (++guard > 20000000) break;   // fail-safe: never hang the bench
            }
        }
        __syncthreads();
        __threadfence();   // acquire for all threads before next step's h loads
    }
}

// decoder + loss: rows R = t*64+b of hs[1..512]; 32 rows/block staged in LDS
__global__ __launch_bounds__(256) void k_dec(const u16* __restrict__ hs, const float* __restrict__ Wd,
                                             const float* __restrict__ bd, const float* __restrict__ Y,
                                             float* __restrict__ out) {
    __shared__ u16 sH[32 * H_];
    __shared__ float red[4];
    int tid = threadIdx.x;
    int R0 = blockIdx.x * 32;
    for (int u = tid; u < 2048; u += 256) {
        int row = u >> 6, ch = u & 63;
        *(short8*)(sH + row * H_ + ch * 8) =
            *(const short8*)(hs + (size_t)(64 + R0 + row) * H_ + ch * 8);
    }
    __syncthreads();

    int n = tid & 127, half = tid >> 7;
    float bdv = bd[n];
    float acc[16];
#pragma unroll
    for (int i = 0; i < 16; ++i) acc[i] = 0.f;

    for (int ko = 0; ko < H_ / 8; ++ko) {
        float wv[8];
#pragma unroll
        for (int j = 0; j < 8; ++j) wv[j] = Wd[(ko * 8 + j) * N_ + n];
#pragma unroll
        for (int i = 0; i < 16; ++i) {
            int r = half * 16 + i;
            const uint4 hv = *(const uint4*)(sH + r * H_ + ko * 8);   // 8 bf16, LDS broadcast
            acc[i] += __uint_as_float(hv.x << 16) * wv[0] + __uint_as_float(hv.x & 0xFFFF0000u) * wv[1]
                    + __uint_as_float(hv.y << 16) * wv[2] + __uint_as_float(hv.y & 0xFFFF0000u) * wv[3]
                    + __uint_as_float(hv.z << 16) * wv[4] + __uint_as_float(hv.z & 0xFFFF0000u) * wv[5]
                    + __uint_as_float(hv.w << 16) * wv[6] + __uint_as_float(hv.w & 0xFFFF0000u) * wv[7];
        }
    }
    float sse = 0.f;
#pragma unroll
    for (int i = 0; i < 16; ++i) {
        int R = R0 + half * 16 + i;
        int t = R >> 6, b = R & 63;
        float logit = sigf(acc[i] + bdv);
        float d = Y[(size_t)(b * T_ + t) * N_ + n] - logit;
        sse += d * d;
    }
    for (int off = 32; off > 0; off >>= 1) sse += __shfl_down(sse, off, 64);
    if ((tid & 63) == 0) red[tid >> 6] = sse;
    __syncthreads();
    if (tid == 0) {
        float tot = red[0] + red[1] + red[2] + red[3];
        atomicAdd(out, tot * (100.0f / 4194304.0f));
    }
}

extern "C" void kernel_launch(void* const* d_in, const int* in_sizes, int n_in,
                              void* d_out, int out_size, void* d_ws, size_t ws_size,
                              hipStream_t stream) {
    (void)in_sizes; (void)n_in; (void)out_size;
    const float* X  = (const float*)d_in[0];
    const float* Y  = (const float*)d_in[1];
    const float* Wx = (const float*)d_in[2];
    const float* Wh = (const float*)d_in[3];
    const float* bb = (const float*)d_in[4];
    const float* Wd = (const float*)d_in[5];
    const float* bd = (const float*)d_in[6];

    char* ws = (char*)d_ws;
    u32* cnt = (u32*)ws;
    u16* hs  = (u16*)(ws + 256);
    const size_t hs_bytes = (size_t)(T_ + 1) * 64 * H_ * 2;          // 33,619,968
    u16* Xb  = (u16*)(ws + 256 + hs_bytes);
    const size_t xb_bytes = (size_t)T_ * 64 * N_ * 2;                // 8,388,608
    u16* Wt  = (u16*)(ws + 256 + hs_bytes + xb_bytes);
    const size_t need = 256 + hs_bytes + xb_bytes + (size_t)2048 * KDIM * 2;
    if (ws_size < need) return;   // ~44.6 MB scratch required

    hipMemsetAsync(cnt, 0, 256, stream);
    hipMemsetAsync(hs, 0, 64 * H_ * 2, stream);      // h_{-1} = 0
    hipMemsetAsync(d_out, 0, sizeof(float), stream);

    k_xb<<<dim3((B_ * T_ * N_) / 256), dim3(256), 0, stream>>>(X, Xb);
    k_wcat<<<dim3((2048 * KDIM) / 256), dim3(256), 0, stream>>>(Wx, Wh, Wt);

    void* args[] = { (void*)&Wt, (void*)&Xb, (void*)&hs, (void*)&bb, (void*)&cnt };
    hipLaunchCooperativeKernel((const void*)k_lstm, dim3(NWG), dim3(256), args, 0, stream);

    k_dec<<<dim3((B_ * T_) / 32), dim3(256), 0, stream>>>(hs, Wd, bd, Y, (float*)d_out);
}

// Round 3
// 5580.890 us; speedup vs baseline: 1.7511x; 1.7511x over previous
//
#include <hip/hip_runtime.h>
#include <stdint.h>

typedef unsigned short u16;
typedef unsigned int u32;

#define B_ 64
#define T_ 512
#define N_ 128
#define H_ 512
#define NWG 64
#define KDIM 640      // H + N
#define PITCH 648     // KDIM + 8 bf16 pad -> LDS row stride 1296B; word-stride%8==4 -> b128 conflict-free
#define GLP 33        // gate LDS pitch (fp32)
#define FLAG_STRIDE 32  // u32s -> 128B per flag line

typedef __attribute__((ext_vector_type(8))) short short8;
typedef __attribute__((ext_vector_type(4))) float floatx4;

__device__ __forceinline__ float sigf(float x) { return 1.0f / (1.0f + __expf(-x)); }
__device__ __forceinline__ float tanh_(float x) { return 1.0f - 2.0f / (1.0f + __expf(2.0f * x)); }

__device__ __forceinline__ u16 f2bf(float x) {
    u32 u = __float_as_uint(x);
    u32 r = (u + 0x7FFFu + ((u >> 16) & 1u)) >> 16;   // RNE
    return (u16)r;
}

// X [B,T,N] fp32 -> Xb [T,B,N] bf16 (time-major so each step's x is contiguous)
__global__ __launch_bounds__(256) void k_xb(const float* __restrict__ X, u16* __restrict__ Xb) {
    int i = blockIdx.x * 256 + threadIdx.x;     // i = t*8192 + b*128 + n
    int n = i & 127, b = (i >> 7) & 63, t = i >> 13;
    Xb[i] = f2bf(X[(b * T_ + t) * N_ + n]);
}

// Wcat^T [2048 cols][640 k] bf16: rows k<512 from Wh, k>=512 from Wx
__global__ __launch_bounds__(256) void k_wcat(const float* __restrict__ Wx, const float* __restrict__ Wh,
                                              u16* __restrict__ Wt) {
    int i = blockIdx.x * 256 + threadIdx.x;     // i = k*2048 + c  (coalesced reads)
    int c = i & 2047, k = i >> 11;
    float v = (k < H_) ? Wh[k * 2048 + c] : Wx[(k - H_) * 2048 + c];
    Wt[c * KDIM + k] = f2bf(v);
}

// Persistent cooperative LSTM. WG w owns h-indices [8w, 8w+8) -> 32 gate cols.
// hs: [513][64][512] bf16 rolling h buffer; step t reads hs[t], writes hs[t+1].
// Sync: per-WG 128B-spaced flags (steps completed), relaxed polls, one acquire
// fence per step. h stores are agent-scope relaxed atomics (write-through to
// LLC; keeps L2 clean so the release fence's wbl2 is cheap). No RMW contention.
__global__ __launch_bounds__(256, 1) void k_lstm(const u16* __restrict__ Wt, const u16* __restrict__ Xb,
                                                 u16* __restrict__ hs, const float* __restrict__ bias,
                                                 u32* __restrict__ flags) {
    __shared__ u16 sInp[64 * PITCH];   // [h | x] staged per step, 82944B
    __shared__ u16 sW[32 * PITCH];     // weight slice (read once into regs), 41472B
    __shared__ float sG[64 * GLP];     // gate outputs, 8448B
    __shared__ float sB[32];

    const int tid = threadIdx.x;
    const int w = blockIdx.x;
    const int lane = tid & 63, wv = tid >> 6;
    const int l16 = lane & 15, quad = lane >> 4;

    // one-time: weight slice -> LDS. local col lc = g*8 + jj -> global col g*512 + w*8 + jj
    for (int u = tid; u < 32 * 80; u += 256) {
        int lc = u / 80, ch = u - lc * 80;
        int gc = (lc >> 3) * H_ + w * 8 + (lc & 7);
        short8 v = *(const short8*)(Wt + (size_t)gc * KDIM + ch * 8);
        *(short8*)(sW + lc * PITCH + ch * 8) = v;
    }
    if (tid < 32) {
        int gc = (tid >> 3) * H_ + w * 8 + (tid & 7);
        sB[tid] = bias[gc] + (((tid >> 3) == 2) ? 1.0f : 0.0f);   // fold forget_bias into f
    }
    __syncthreads();

    // hoist static B fragments into registers (1 wave/SIMD -> ~512 VGPR budget).
    // removes 40 of 60 ds_read_b128 per wave per step.
    short8 bfrag0[KDIM / 32], bfrag1[KDIM / 32];
    {
        const u16* brow0 = sW + l16 * PITCH + quad * 8;
        const u16* brow1 = sW + (16 + l16) * PITCH + quad * 8;
#pragma unroll
        for (int ks = 0; ks < KDIM / 32; ++ks) {
            bfrag0[ks] = *(const short8*)(brow0 + ks * 32);
            bfrag1[ks] = *(const short8*)(brow1 + ks * 32);
        }
    }

    // gate-math mapping: thread owns (b, jj0) and (b, jj0+1); c persists in regs
    const int gb = tid >> 2;
    const int jj0 = (tid & 3) * 2;
    float c0 = 0.f, c1 = 0.f;

    for (int t = 0; t < T_; ++t) {
        // stage x_t (read-only, no cross-step dependency) before waiting on flags
        const u16* xsrc = Xb + (size_t)t * (64 * N_);
        for (int u = tid; u < 1024; u += 256) {
            int b = u >> 4, ch = u & 15;
            short8 v = *(const short8*)(xsrc + b * N_ + ch * 8);
            *(short8*)(sInp + b * PITCH + H_ + ch * 8) = v;
        }

        // wait for all producers of hs[t]: 64 threads poll 64 distinct flag lines
        if (t > 0 && tid < NWG) {
            const u32* f = flags + tid * FLAG_STRIDE;
            int guard = 0;
            while (__hip_atomic_load(f, __ATOMIC_RELAXED, __HIP_MEMORY_SCOPE_AGENT) < (u32)t) {
                __builtin_amdgcn_s_sleep(2);
                if (++guard > 1000000) break;   // fail-safe: never hang the bench
            }
        }
        __syncthreads();
        if (t > 0) __builtin_amdgcn_fence(__ATOMIC_ACQUIRE, "agent");

        // stage h_t (plain vector loads; acquire fence above invalidated stale lines)
        const u16* hsrc = hs + (size_t)t * (64 * H_);
        for (int u = tid; u < 4096; u += 256) {
            int b = u >> 6, ch = u & 63;
            short8 v = *(const short8*)(hsrc + b * H_ + ch * 8);
            *(short8*)(sInp + b * PITCH + ch * 8) = v;
        }
        __syncthreads();

        // wave wv: M-tile = batches [16wv,16wv+16), N-tiles: cols 0..15 (i,j), 16..31 (f,o)
        floatx4 acc0 = {0.f, 0.f, 0.f, 0.f}, acc1 = {0.f, 0.f, 0.f, 0.f};
        const u16* arow = sInp + (16 * wv + l16) * PITCH + quad * 8;
#pragma unroll
        for (int ks = 0; ks < KDIM / 32; ++ks) {
            short8 a = *(const short8*)(arow + ks * 32);
            acc0 = __builtin_amdgcn_mfma_f32_16x16x32_bf16(a, bfrag0[ks], acc0, 0, 0, 0);
            acc1 = __builtin_amdgcn_mfma_f32_16x16x32_bf16(a, bfrag1[ks], acc1, 0, 0, 0);
        }
        // C/D layout: col = lane&15, row = quad*4 + reg  (m89-verified)
        int gbr = 16 * wv + quad * 4;
#pragma unroll
        for (int r = 0; r < 4; ++r) {
            sG[(gbr + r) * GLP + l16]      = acc0[r];
            sG[(gbr + r) * GLP + 16 + l16] = acc1[r];
        }
        __syncthreads();

        // gate math: cols [i0..7 | j0..7 | f0..7 | o0..7]
        float iv0 = sG[gb * GLP + jj0]          + sB[jj0];
        float iv1 = sG[gb * GLP + jj0 + 1]      + sB[jj0 + 1];
        float jv0 = sG[gb * GLP + 8 + jj0]      + sB[8 + jj0];
        float jv1 = sG[gb * GLP + 8 + jj0 + 1]  + sB[8 + jj0 + 1];
        float fv0 = sG[gb * GLP + 16 + jj0]     + sB[16 + jj0];
        float fv1 = sG[gb * GLP + 16 + jj0 + 1] + sB[16 + jj0 + 1];
        float ov0 = sG[gb * GLP + 24 + jj0]     + sB[24 + jj0];
        float ov1 = sG[gb * GLP + 24 + jj0 + 1] + sB[24 + jj0 + 1];

        c0 = sigf(fv0) * c0 + sigf(iv0) * tanh_(jv0);
        c1 = sigf(fv1) * c1 + sigf(iv1) * tanh_(jv1);
        float h0 = sigf(ov0) * tanh_(c0);
        float h1 = sigf(ov1) * tanh_(c1);
        u32 packed = ((u32)f2bf(h1) << 16) | (u32)f2bf(h0);
        // write-through to LLC (agent-scope relaxed atomic): visible without L2 wb
        u32* hdst = (u32*)(hs + (size_t)(t + 1) * (64 * H_) + gb * H_ + w * 8 + jj0);
        __hip_atomic_store(hdst, packed, __ATOMIC_RELAXED, __HIP_MEMORY_SCOPE_AGENT);

        // release own store, barrier so all 256 threads' stores are ordered, publish flag
        __builtin_amdgcn_fence(__ATOMIC_RELEASE, "agent");
        __syncthreads();
        if (tid == 0)
            __hip_atomic_store(flags + w * FLAG_STRIDE, (u32)(t + 1),
                               __ATOMIC_RELEASE, __HIP_MEMORY_SCOPE_AGENT);
    }
}

// decoder + loss: rows R = t*64+b of hs[1..512]; 32 rows/block staged in LDS
__global__ __launch_bounds__(256) void k_dec(const u16* __restrict__ hs, const float* __restrict__ Wd,
                                             const float* __restrict__ bd, const float* __restrict__ Y,
                                             float* __restrict__ out) {
    __shared__ u16 sH[32 * H_];
    __shared__ float red[4];
    int tid = threadIdx.x;
    int R0 = blockIdx.x * 32;
    for (int u = tid; u < 2048; u += 256) {
        int row = u >> 6, ch = u & 63;
        *(short8*)(sH + row * H_ + ch * 8) =
            *(const short8*)(hs + (size_t)(64 + R0 + row) * H_ + ch * 8);
    }
    __syncthreads();

    int n = tid & 127, half = tid >> 7;
    float bdv = bd[n];
    float acc[16];
#pragma unroll
    for (int i = 0; i < 16; ++i) acc[i] = 0.f;

    for (int ko = 0; ko < H_ / 8; ++ko) {
        float wv[8];
#pragma unroll
        for (int j = 0; j < 8; ++j) wv[j] = Wd[(ko * 8 + j) * N_ + n];
#pragma unroll
        for (int i = 0; i < 16; ++i) {
            int r = half * 16 + i;
            const uint4 hv = *(const uint4*)(sH + r * H_ + ko * 8);   // 8 bf16, LDS broadcast
            acc[i] += __uint_as_float(hv.x << 16) * wv[0] + __uint_as_float(hv.x & 0xFFFF0000u) * wv[1]
                    + __uint_as_float(hv.y << 16) * wv[2] + __uint_as_float(hv.y & 0xFFFF0000u) * wv[3]
                    + __uint_as_float(hv.z << 16) * wv[4] + __uint_as_float(hv.z & 0xFFFF0000u) * wv[5]
                    + __uint_as_float(hv.w << 16) * wv[6] + __uint_as_float(hv.w & 0xFFFF0000u) * wv[7];
        }
    }
    float sse = 0.f;
#pragma unroll
    for (int i = 0; i < 16; ++i) {
        int R = R0 + half * 16 + i;
        int t = R >> 6, b = R & 63;
        float logit = sigf(acc[i] + bdv);
        float d = Y[(size_t)(b * T_ + t) * N_ + n] - logit;
        sse += d * d;
    }
    for (int off = 32; off > 0; off >>= 1) sse += __shfl_down(sse, off, 64);
    if ((tid & 63) == 0) red[tid >> 6] = sse;
    __syncthreads();
    if (tid == 0) {
        float tot = red[0] + red[1] + red[2] + red[3];
        atomicAdd(out, tot * (100.0f / 4194304.0f));
    }
}

extern "C" void kernel_launch(void* const* d_in, const int* in_sizes, int n_in,
                              void* d_out, int out_size, void* d_ws, size_t ws_size,
                              hipStream_t stream) {
    (void)in_sizes; (void)n_in; (void)out_size;
    const float* X  = (const float*)d_in[0];
    const float* Y  = (const float*)d_in[1];
    const float* Wx = (const float*)d_in[2];
    const float* Wh = (const float*)d_in[3];
    const float* bb = (const float*)d_in[4];
    const float* Wd = (const float*)d_in[5];
    const float* bd = (const float*)d_in[6];

    char* ws = (char*)d_ws;
    u32* flags = (u32*)ws;                     // 64 flags x 128B = 8KB
    const size_t flag_bytes = 16384;
    u16* hs  = (u16*)(ws + flag_bytes);
    const size_t hs_bytes = (size_t)(T_ + 1) * 64 * H_ * 2;          // 33,619,968
    u16* Xb  = (u16*)(ws + flag_bytes + hs_bytes);
    const size_t xb_bytes = (size_t)T_ * 64 * N_ * 2;                // 8,388,608
    u16* Wt  = (u16*)(ws + flag_bytes + hs_bytes + xb_bytes);
    const size_t need = flag_bytes + hs_bytes + xb_bytes + (size_t)2048 * KDIM * 2;
    if (ws_size < need) return;   // ~44.6 MB scratch required

    (void)hipMemsetAsync(flags, 0, flag_bytes, stream);
    (void)hipMemsetAsync(hs, 0, 64 * H_ * 2, stream);      // h_{-1} = 0
    (void)hipMemsetAsync(d_out, 0, sizeof(float), stream);

    k_xb<<<dim3((B_ * T_ * N_) / 256), dim3(256), 0, stream>>>(X, Xb);
    k_wcat<<<dim3((2048 * KDIM) / 256), dim3(256), 0, stream>>>(Wx, Wh, Wt);

    void* args[] = { (void*)&Wt, (void*)&Xb, (void*)&hs, (void*)&bb, (void*)&flags };
    (void)hipLaunchCooperativeKernel((const void*)k_lstm, dim3(NWG), dim3(256), args, 0, stream);

    k_dec<<<dim3((B_ * T_) / 32), dim3(256), 0, stream>>>(hs, Wd, bd, Y, (float*)d_out);
}

// Round 4
// 4394.467 us; speedup vs baseline: 2.2239x; 1.2700x over previous
//
#include <hip/hip_runtime.h>
#include <stdint.h>

typedef unsigned short u16;
typedef unsigned int u32;
typedef unsigned long long u64;

#define B_ 64
#define T_ 512
#define N_ 128
#define H_ 512
#define NWG 64
#define KDIM 640      // H + N
#define PITCH 648     // LDS row stride for weight slice (pad keeps b128 reads conflict-free)
#define GLP 33        // gate LDS pitch (fp32)
#define FLAG_STRIDE 32  // u32s -> 128B per flag line; 256 flags (one per wave)

typedef __attribute__((ext_vector_type(8))) short short8;
typedef __attribute__((ext_vector_type(4))) float floatx4;
typedef __attribute__((ext_vector_type(2))) u64 ulong2_t;

__device__ __forceinline__ float sigf(float x) { return 1.0f / (1.0f + __expf(-x)); }
__device__ __forceinline__ float tanh_(float x) { return 1.0f - 2.0f / (1.0f + __expf(2.0f * x)); }

__device__ __forceinline__ u16 f2bf(float x) {
    u32 u = __float_as_uint(x);
    u32 r = (u + 0x7FFFu + ((u >> 16) & 1u)) >> 16;   // RNE
    return (u16)r;
}

// X [B,T,N] fp32 -> Xb [T,B,N] bf16 (time-major so each step's x is contiguous)
__global__ __launch_bounds__(256) void k_xb(const float* __restrict__ X, u16* __restrict__ Xb) {
    int i = blockIdx.x * 256 + threadIdx.x;     // i = t*8192 + b*128 + n
    int n = i & 127, b = (i >> 7) & 63, t = i >> 13;
    Xb[i] = f2bf(X[(b * T_ + t) * N_ + n]);
}

// Wcat^T [2048 cols][640 k] bf16: rows k<512 from Wh, k>=512 from Wx
__global__ __launch_bounds__(256) void k_wcat(const float* __restrict__ Wx, const float* __restrict__ Wh,
                                              u16* __restrict__ Wt) {
    int i = blockIdx.x * 256 + threadIdx.x;     // i = k*2048 + c  (coalesced reads)
    int c = i & 2047, k = i >> 11;
    float v = (k < H_) ? Wh[k * 2048 + c] : Wx[(k - H_) * 2048 + c];
    Wt[c * KDIM + k] = f2bf(v);
}

// Persistent cooperative LSTM, fence-free sc1 datapath.
// Wave (w,wv) owns: M-tile = batches [16wv,16wv+16), cols {g*512 + w*8+j}.
// All h exchange via agent-scope relaxed atomics (write-through LLC / bypass L2).
// 256 per-wave flags; no per-step __syncthreads at all — waves free-run.
__global__ __launch_bounds__(256, 1) void k_lstm(const u16* __restrict__ Wt, const u16* __restrict__ Xb,
                                                 u16* __restrict__ hs, const float* __restrict__ bias,
                                                 u32* __restrict__ flags) {
    __shared__ u16 sW[32 * PITCH];     // weight slice (read once into regs), 41472B
    __shared__ float sG[64 * GLP];     // gate outputs (per-wave private rows), 8448B
    __shared__ float sB[32];

    const int tid = threadIdx.x;
    const int w = blockIdx.x;
    const int lane = tid & 63, wv = tid >> 6;
    const int l16 = lane & 15, quad = lane >> 4;

    // one-time: weight slice -> LDS. local col lc = g*8 + jj -> global col g*512 + w*8 + jj
    for (int u = tid; u < 32 * 80; u += 256) {
        int lc = u / 80, ch = u - lc * 80;
        int gc = (lc >> 3) * H_ + w * 8 + (lc & 7);
        short8 v = *(const short8*)(Wt + (size_t)gc * KDIM + ch * 8);
        *(short8*)(sW + lc * PITCH + ch * 8) = v;
    }
    if (tid < 32) {
        int gc = (tid >> 3) * H_ + w * 8 + (tid & 7);
        sB[tid] = bias[gc] + (((tid >> 3) == 2) ? 1.0f : 0.0f);   // fold forget_bias into f
    }
    __syncthreads();

    // hoist static B fragments into registers (1 wave/SIMD -> ~512 VGPR budget)
    short8 bfrag0[KDIM / 32], bfrag1[KDIM / 32];
    {
        const u16* brow0 = sW + l16 * PITCH + quad * 8;
        const u16* brow1 = sW + (16 + l16) * PITCH + quad * 8;
#pragma unroll
        for (int ks = 0; ks < KDIM / 32; ++ks) {
            bfrag0[ks] = *(const short8*)(brow0 + ks * 32);
            bfrag1[ks] = *(const short8*)(brow1 + ks * 32);
        }
    }

    // gate-math mapping (intra-wave): batch row gb, cols w*8 + {jj0, jj0+1}
    const int gb = 16 * wv + (lane >> 2);
    const int jj0 = (lane & 3) * 2;
    float c0 = 0.f, c1 = 0.f;

    for (int t = 0; t < T_; ++t) {
        // wait for ALL 256 producer waves of hs[t] (relaxed sc1 polls, no fences)
        if (t > 0) {
            const u32 tt = (u32)t;
            int guard = 0;
            for (;;) {
                u32 v0 = __hip_atomic_load(flags + (lane)       * FLAG_STRIDE, __ATOMIC_RELAXED, __HIP_MEMORY_SCOPE_AGENT);
                u32 v1 = __hip_atomic_load(flags + (lane + 64)  * FLAG_STRIDE, __ATOMIC_RELAXED, __HIP_MEMORY_SCOPE_AGENT);
                u32 v2 = __hip_atomic_load(flags + (lane + 128) * FLAG_STRIDE, __ATOMIC_RELAXED, __HIP_MEMORY_SCOPE_AGENT);
                u32 v3 = __hip_atomic_load(flags + (lane + 192) * FLAG_STRIDE, __ATOMIC_RELAXED, __HIP_MEMORY_SCOPE_AGENT);
                bool ok = (v0 >= tt) & (v1 >= tt) & (v2 >= tt) & (v3 >= tt);
                if (__all(ok)) break;
                __builtin_amdgcn_s_sleep(1);
                if (++guard > 200000) break;   // fail-safe: never hang the bench
            }
            asm volatile("" ::: "memory");     // no load speculation above the poll
        }

        // A-fragments straight from LLC into registers (no LDS staging).
        // h part (K 0..511): sc1 u64 atomic loads; x part (K 512..639): cached loads.
        short8 afr[KDIM / 32];
        const u16* hrow = hs + (size_t)t * (64 * H_) + (16 * wv + l16) * H_ + quad * 8;
#pragma unroll
        for (int ks = 0; ks < 16; ++ks) {
            const u64* p = (const u64*)(hrow + ks * 32);
            ulong2_t tmp;
            tmp.x = __hip_atomic_load(p,     __ATOMIC_RELAXED, __HIP_MEMORY_SCOPE_AGENT);
            tmp.y = __hip_atomic_load(p + 1, __ATOMIC_RELAXED, __HIP_MEMORY_SCOPE_AGENT);
            afr[ks] = __builtin_bit_cast(short8, tmp);
        }
        const u16* xrow = Xb + (size_t)t * (64 * N_) + (16 * wv + l16) * N_ + quad * 8;
#pragma unroll
        for (int ks = 0; ks < 4; ++ks) afr[16 + ks] = *(const short8*)(xrow + ks * 32);

        floatx4 acc0 = {0.f, 0.f, 0.f, 0.f}, acc1 = {0.f, 0.f, 0.f, 0.f};
#pragma unroll
        for (int ks = 0; ks < KDIM / 32; ++ks) {
            acc0 = __builtin_amdgcn_mfma_f32_16x16x32_bf16(afr[ks], bfrag0[ks], acc0, 0, 0, 0);
            acc1 = __builtin_amdgcn_mfma_f32_16x16x32_bf16(afr[ks], bfrag1[ks], acc1, 0, 0, 0);
        }

        // C/D layout: col = lane&15, row = quad*4 + reg. sG rows are wave-private ->
        // only intra-wave LDS ordering needed (lgkmcnt), no barrier.
        int gbr = 16 * wv + quad * 4;
#pragma unroll
        for (int r = 0; r < 4; ++r) {
            sG[(gbr + r) * GLP + l16]      = acc0[r];
            sG[(gbr + r) * GLP + 16 + l16] = acc1[r];
        }
        asm volatile("s_waitcnt lgkmcnt(0)" ::: "memory");

        // gate math: cols [i0..7 | j0..7 | f0..7 | o0..7]
        float iv0 = sG[gb * GLP + jj0]          + sB[jj0];
        float iv1 = sG[gb * GLP + jj0 + 1]      + sB[jj0 + 1];
        float jv0 = sG[gb * GLP + 8 + jj0]      + sB[8 + jj0];
        float jv1 = sG[gb * GLP + 8 + jj0 + 1]  + sB[8 + jj0 + 1];
        float fv0 = sG[gb * GLP + 16 + jj0]     + sB[16 + jj0];
        float fv1 = sG[gb * GLP + 16 + jj0 + 1] + sB[16 + jj0 + 1];
        float ov0 = sG[gb * GLP + 24 + jj0]     + sB[24 + jj0];
        float ov1 = sG[gb * GLP + 24 + jj0 + 1] + sB[24 + jj0 + 1];

        c0 = sigf(fv0) * c0 + sigf(iv0) * tanh_(jv0);
        c1 = sigf(fv1) * c1 + sigf(iv1) * tanh_(jv1);
        float h0 = sigf(ov0) * tanh_(c0);
        float h1 = sigf(ov1) * tanh_(c1);
        u32 packed = ((u32)f2bf(h1) << 16) | (u32)f2bf(h0);
        u32* hdst = (u32*)(hs + (size_t)(t + 1) * (64 * H_) + gb * H_ + w * 8 + jj0);
        __hip_atomic_store(hdst, packed, __ATOMIC_RELAXED, __HIP_MEMORY_SCOPE_AGENT);

        // drain own sc1 stores to LLC, then publish this wave's flag
        asm volatile("s_waitcnt vmcnt(0)" ::: "memory");
        if (lane == 0)
            __hip_atomic_store(flags + (w * 4 + wv) * FLAG_STRIDE, (u32)(t + 1),
                               __ATOMIC_RELAXED, __HIP_MEMORY_SCOPE_AGENT);
    }
}

// decoder + loss: rows R = t*64+b of hs[1..512]; 32 rows/block staged in LDS
__global__ __launch_bounds__(256) void k_dec(const u16* __restrict__ hs, const float* __restrict__ Wd,
                                             const float* __restrict__ bd, const float* __restrict__ Y,
                                             float* __restrict__ out) {
    __shared__ u16 sH[32 * H_];
    __shared__ float red[4];
    int tid = threadIdx.x;
    int R0 = blockIdx.x * 32;
    for (int u = tid; u < 2048; u += 256) {
        int row = u >> 6, ch = u & 63;
        *(short8*)(sH + row * H_ + ch * 8) =
            *(const short8*)(hs + (size_t)(64 + R0 + row) * H_ + ch * 8);
    }
    __syncthreads();

    int n = tid & 127, half = tid >> 7;
    float bdv = bd[n];
    float acc[16];
#pragma unroll
    for (int i = 0; i < 16; ++i) acc[i] = 0.f;

    for (int ko = 0; ko < H_ / 8; ++ko) {
        float wv[8];
#pragma unroll
        for (int j = 0; j < 8; ++j) wv[j] = Wd[(ko * 8 + j) * N_ + n];
#pragma unroll
        for (int i = 0; i < 16; ++i) {
            int r = half * 16 + i;
            const uint4 hv = *(const uint4*)(sH + r * H_ + ko * 8);   // 8 bf16, LDS broadcast
            acc[i] += __uint_as_float(hv.x << 16) * wv[0] + __uint_as_float(hv.x & 0xFFFF0000u) * wv[1]
                    + __uint_as_float(hv.y << 16) * wv[2] + __uint_as_float(hv.y & 0xFFFF0000u) * wv[3]
                    + __uint_as_float(hv.z << 16) * wv[4] + __uint_as_float(hv.z & 0xFFFF0000u) * wv[5]
                    + __uint_as_float(hv.w << 16) * wv[6] + __uint_as_float(hv.w & 0xFFFF0000u) * wv[7];
        }
    }
    float sse = 0.f;
#pragma unroll
    for (int i = 0; i < 16; ++i) {
        int R = R0 + half * 16 + i;
        int t = R >> 6, b = R & 63;
        float logit = sigf(acc[i] + bdv);
        float d = Y[(size_t)(b * T_ + t) * N_ + n] - logit;
        sse += d * d;
    }
    for (int off = 32; off > 0; off >>= 1) sse += __shfl_down(sse, off, 64);
    if ((tid & 63) == 0) red[tid >> 6] = sse;
    __syncthreads();
    if (tid == 0) {
        float tot = red[0] + red[1] + red[2] + red[3];
        atomicAdd(out, tot * (100.0f / 4194304.0f));
    }
}

extern "C" void kernel_launch(void* const* d_in, const int* in_sizes, int n_in,
                              void* d_out, int out_size, void* d_ws, size_t ws_size,
                              hipStream_t stream) {
    (void)in_sizes; (void)n_in; (void)out_size;
    const float* X  = (const float*)d_in[0];
    const float* Y  = (const float*)d_in[1];
    const float* Wx = (const float*)d_in[2];
    const float* Wh = (const float*)d_in[3];
    const float* bb = (const float*)d_in[4];
    const float* Wd = (const float*)d_in[5];
    const float* bd = (const float*)d_in[6];

    char* ws = (char*)d_ws;
    u32* flags = (u32*)ws;                     // 256 flags x 128B = 32KB
    const size_t flag_bytes = 32768;
    u16* hs  = (u16*)(ws + flag_bytes);
    const size_t hs_bytes = (size_t)(T_ + 1) * 64 * H_ * 2;          // 33,619,968
    u16* Xb  = (u16*)(ws + flag_bytes + hs_bytes);
    const size_t xb_bytes = (size_t)T_ * 64 * N_ * 2;                // 8,388,608
    u16* Wt  = (u16*)(ws + flag_bytes + hs_bytes + xb_bytes);
    const size_t need = flag_bytes + hs_bytes + xb_bytes + (size_t)2048 * KDIM * 2;
    if (ws_size < need) return;   // ~44.7 MB scratch required

    (void)hipMemsetAsync(flags, 0, flag_bytes, stream);
    (void)hipMemsetAsync(hs, 0, 64 * H_ * 2, stream);      // h_{-1} = 0
    (void)hipMemsetAsync(d_out, 0, sizeof(float), stream);

    k_xb<<<dim3((B_ * T_ * N_) / 256), dim3(256), 0, stream>>>(X, Xb);
    k_wcat<<<dim3((2048 * KDIM) / 256), dim3(256), 0, stream>>>(Wx, Wh, Wt);

    void* args[] = { (void*)&Wt, (void*)&Xb, (void*)&hs, (void*)&bb, (void*)&flags };
    (void)hipLaunchCooperativeKernel((const void*)k_lstm, dim3(NWG), dim3(256), args, 0, stream);

    k_dec<<<dim3((B_ * T_) / 32), dim3(256), 0, stream>>>(hs, Wd, bd, Y, (float*)d_out);
}

// Round 5
// 3175.628 us; speedup vs baseline: 3.0774x; 1.3838x over previous
//
#include <hip/hip_runtime.h>
#include <stdint.h>

typedef unsigned short u16;
typedef unsigned int u32;
typedef unsigned long long u64;

#define B_ 64
#define T_ 512
#define N_ 128
#define H_ 512
#define NWG 64
#define KDIM 640      // H + N
#define PITCH 648     // LDS row stride for weight slice (pad keeps b128 reads conflict-free)
#define GLP 33        // gate LDS pitch (fp32)
#define FLAG_STRIDE 32  // u32s -> 128B per flag line; 64 flags (one per WG)

typedef __attribute__((ext_vector_type(8))) short short8;
typedef __attribute__((ext_vector_type(4))) float floatx4;
typedef __attribute__((ext_vector_type(2))) u64 ulong2_t;

__device__ __forceinline__ float sigf(float x) { return 1.0f / (1.0f + __expf(-x)); }
__device__ __forceinline__ float tanh_(float x) { return 1.0f - 2.0f / (1.0f + __expf(2.0f * x)); }

__device__ __forceinline__ u16 f2bf(float x) {
    u32 u = __float_as_uint(x);
    u32 r = (u + 0x7FFFu + ((u >> 16) & 1u)) >> 16;   // RNE
    return (u16)r;
}

// X [B,T,N] fp32 -> Xb [T,B,N] bf16 (time-major so each step's x is contiguous)
__global__ __launch_bounds__(256) void k_xb(const float* __restrict__ X, u16* __restrict__ Xb) {
    int i = blockIdx.x * 256 + threadIdx.x;     // i = t*8192 + b*128 + n
    int n = i & 127, b = (i >> 7) & 63, t = i >> 13;
    Xb[i] = f2bf(X[(b * T_ + t) * N_ + n]);
}

// Wcat^T [2048 cols][640 k] bf16: rows k<512 from Wh, k>=512 from Wx
__global__ __launch_bounds__(256) void k_wcat(const float* __restrict__ Wx, const float* __restrict__ Wh,
                                              u16* __restrict__ Wt) {
    int i = blockIdx.x * 256 + threadIdx.x;     // i = k*2048 + c  (coalesced reads)
    int c = i & 2047, k = i >> 11;
    float v = (k < H_) ? Wh[k * 2048 + c] : Wx[(k - H_) * 2048 + c];
    Wt[c * KDIM + k] = f2bf(v);
}

// Persistent cooperative LSTM, fence-free sc1 datapath, hierarchical sync.
// Wave (w,wv) owns: M-tile = batches [16wv,16wv+16), cols {g*512 + w*8+j}.
// Sync per step: each wave drains h stores (vmcnt0), __syncthreads, tid0
// publishes ONE per-WG flag; wave 0 polls the 64 WG flags (1 line/lane) and
// publishes an LDS epoch; waves 1-3 spin on LDS. LLC poll traffic is 16x
// lower than all-to-all wave flags (R4's suspected contention source).
__global__ __launch_bounds__(256, 1) void k_lstm(const u16* __restrict__ Wt, const u16* __restrict__ Xb,
                                                 u16* __restrict__ hs, const float* __restrict__ bias,
                                                 u32* __restrict__ flags) {
    __shared__ u16 sW[32 * PITCH];     // weight slice, 41472B
    __shared__ float sG[64 * GLP];     // gate outputs (per-wave private rows), 8448B
    __shared__ float sB[32];
    __shared__ int sEpoch;

    const int tid = threadIdx.x;
    const int w = blockIdx.x;
    const int lane = tid & 63, wv = tid >> 6;
    const int l16 = lane & 15, quad = lane >> 4;

    if (tid == 0) sEpoch = 0;

    // one-time: weight slice -> LDS. local col lc = g*8 + jj -> global col g*512 + w*8 + jj
    for (int u = tid; u < 32 * 80; u += 256) {
        int lc = u / 80, ch = u - lc * 80;
        int gc = (lc >> 3) * H_ + w * 8 + (lc & 7);
        short8 v = *(const short8*)(Wt + (size_t)gc * KDIM + ch * 8);
        *(short8*)(sW + lc * PITCH + ch * 8) = v;
    }
    if (tid < 32) {
        int gc = (tid >> 3) * H_ + w * 8 + (tid & 7);
        sB[tid] = bias[gc] + (((tid >> 3) == 2) ? 1.0f : 0.0f);   // fold forget_bias into f
    }
    __syncthreads();

    // B fragments (compiler may keep these LDS-resident; either is fine)
    short8 bfrag0[KDIM / 32], bfrag1[KDIM / 32];
    {
        const u16* brow0 = sW + l16 * PITCH + quad * 8;
        const u16* brow1 = sW + (16 + l16) * PITCH + quad * 8;
#pragma unroll
        for (int ks = 0; ks < KDIM / 32; ++ks) {
            bfrag0[ks] = *(const short8*)(brow0 + ks * 32);
            bfrag1[ks] = *(const short8*)(brow1 + ks * 32);
        }
    }

    // gate-math mapping (intra-wave): batch row gb, cols w*8 + {jj0, jj0+1}
    const int gb = 16 * wv + (lane >> 2);
    const int jj0 = (lane & 3) * 2;
    float c0 = 0.f, c1 = 0.f;

    for (int t = 0; t < T_; ++t) {
        // x fragments: independent of the recurrence -> load before the sync wait
        short8 xfr[4];
        const u16* xrow = Xb + (size_t)t * (64 * N_) + (16 * wv + l16) * N_ + quad * 8;
#pragma unroll
        for (int ks = 0; ks < 4; ++ks) xfr[ks] = *(const short8*)(xrow + ks * 32);

        if (t > 0) {
            if (wv == 0) {
                // poller wave: lane i polls WG i's flag (64 distinct lines, 1 per lane)
                const u32* f = flags + lane * FLAG_STRIDE;
                int guard = 0;
                while (__hip_atomic_load(f, __ATOMIC_RELAXED, __HIP_MEMORY_SCOPE_AGENT) < (u32)t) {
                    __builtin_amdgcn_s_sleep(1);
                    if (++guard > 2000000) break;   // fail-safe: never hang the bench
                }
                // reconverged: all 64 producer WGs have published step t
                if (lane == 0)
                    __hip_atomic_store(&sEpoch, t, __ATOMIC_RELAXED, __HIP_MEMORY_SCOPE_WORKGROUP);
            } else {
                // other waves spin on LDS (no LLC traffic)
                int guard = 0;
                while (__hip_atomic_load(&sEpoch, __ATOMIC_RELAXED, __HIP_MEMORY_SCOPE_WORKGROUP) < t) {
                    __builtin_amdgcn_s_sleep(1);
                    if (++guard > 2000000) break;
                }
            }
            asm volatile("" ::: "memory");     // no h-load speculation above the wait
        }

        // h fragments straight from LLC into registers (sc1 u64 atomic loads)
        short8 afr[16];
        const u16* hrow = hs + (size_t)t * (64 * H_) + (16 * wv + l16) * H_ + quad * 8;
#pragma unroll
        for (int ks = 0; ks < 16; ++ks) {
            const u64* p = (const u64*)(hrow + ks * 32);
            ulong2_t tmp;
            tmp.x = __hip_atomic_load(p,     __ATOMIC_RELAXED, __HIP_MEMORY_SCOPE_AGENT);
            tmp.y = __hip_atomic_load(p + 1, __ATOMIC_RELAXED, __HIP_MEMORY_SCOPE_AGENT);
            afr[ks] = __builtin_bit_cast(short8, tmp);
        }

        // MFMA with 2-way split accumulators (halves the dependent-chain depth)
        floatx4 p0 = {0.f,0.f,0.f,0.f}, q0 = {0.f,0.f,0.f,0.f};
        floatx4 p1 = {0.f,0.f,0.f,0.f}, q1 = {0.f,0.f,0.f,0.f};
#pragma unroll
        for (int ks = 0; ks < 16; ks += 2) {
            p0 = __builtin_amdgcn_mfma_f32_16x16x32_bf16(afr[ks],     bfrag0[ks],     p0, 0, 0, 0);
            p1 = __builtin_amdgcn_mfma_f32_16x16x32_bf16(afr[ks],     bfrag1[ks],     p1, 0, 0, 0);
            q0 = __builtin_amdgcn_mfma_f32_16x16x32_bf16(afr[ks + 1], bfrag0[ks + 1], q0, 0, 0, 0);
            q1 = __builtin_amdgcn_mfma_f32_16x16x32_bf16(afr[ks + 1], bfrag1[ks + 1], q1, 0, 0, 0);
        }
#pragma unroll
        for (int ks = 0; ks < 4; ks += 2) {
            p0 = __builtin_amdgcn_mfma_f32_16x16x32_bf16(xfr[ks],     bfrag0[16 + ks],     p0, 0, 0, 0);
            p1 = __builtin_amdgcn_mfma_f32_16x16x32_bf16(xfr[ks],     bfrag1[16 + ks],     p1, 0, 0, 0);
            q0 = __builtin_amdgcn_mfma_f32_16x16x32_bf16(xfr[ks + 1], bfrag0[16 + ks + 1], q0, 0, 0, 0);
            q1 = __builtin_amdgcn_mfma_f32_16x16x32_bf16(xfr[ks + 1], bfrag1[16 + ks + 1], q1, 0, 0, 0);
        }
        floatx4 acc0 = p0 + q0, acc1 = p1 + q1;

        // C/D layout: col = lane&15, row = quad*4 + reg. sG rows are wave-private ->
        // only intra-wave LDS ordering needed (lgkmcnt), no barrier.
        int gbr = 16 * wv + quad * 4;
#pragma unroll
        for (int r = 0; r < 4; ++r) {
            sG[(gbr + r) * GLP + l16]      = acc0[r];
            sG[(gbr + r) * GLP + 16 + l16] = acc1[r];
        }
        asm volatile("s_waitcnt lgkmcnt(0)" ::: "memory");

        // gate math: cols [i0..7 | j0..7 | f0..7 | o0..7]
        float iv0 = sG[gb * GLP + jj0]          + sB[jj0];
        float iv1 = sG[gb * GLP + jj0 + 1]      + sB[jj0 + 1];
        float jv0 = sG[gb * GLP + 8 + jj0]      + sB[8 + jj0];
        float jv1 = sG[gb * GLP + 8 + jj0 + 1]  + sB[8 + jj0 + 1];
        float fv0 = sG[gb * GLP + 16 + jj0]     + sB[16 + jj0];
        float fv1 = sG[gb * GLP + 16 + jj0 + 1] + sB[16 + jj0 + 1];
        float ov0 = sG[gb * GLP + 24 + jj0]     + sB[24 + jj0];
        float ov1 = sG[gb * GLP + 24 + jj0 + 1] + sB[24 + jj0 + 1];

        c0 = sigf(fv0) * c0 + sigf(iv0) * tanh_(jv0);
        c1 = sigf(fv1) * c1 + sigf(iv1) * tanh_(jv1);
        float h0 = sigf(ov0) * tanh_(c0);
        float h1 = sigf(ov1) * tanh_(c1);
        u32 packed = ((u32)f2bf(h1) << 16) | (u32)f2bf(h0);
        u32* hdst = (u32*)(hs + (size_t)(t + 1) * (64 * H_) + gb * H_ + w * 8 + jj0);
        __hip_atomic_store(hdst, packed, __ATOMIC_RELAXED, __HIP_MEMORY_SCOPE_AGENT);

        // per-wave drain, WG barrier, single per-WG flag publish
        asm volatile("s_waitcnt vmcnt(0)" ::: "memory");
        __syncthreads();
        if (tid == 0)
            __hip_atomic_store(flags + w * FLAG_STRIDE, (u32)(t + 1),
                               __ATOMIC_RELAXED, __HIP_MEMORY_SCOPE_AGENT);
    }
}

// decoder + loss: rows R = t*64+b of hs[1..512]; 32 rows/block staged in LDS
__global__ __launch_bounds__(256) void k_dec(const u16* __restrict__ hs, const float* __restrict__ Wd,
                                             const float* __restrict__ bd, const float* __restrict__ Y,
                                             float* __restrict__ out) {
    __shared__ u16 sH[32 * H_];
    __shared__ float red[4];
    int tid = threadIdx.x;
    int R0 = blockIdx.x * 32;
    for (int u = tid; u < 2048; u += 256) {
        int row = u >> 6, ch = u & 63;
        *(short8*)(sH + row * H_ + ch * 8) =
            *(const short8*)(hs + (size_t)(64 + R0 + row) * H_ + ch * 8);
    }
    __syncthreads();

    int n = tid & 127, half = tid >> 7;
    float bdv = bd[n];
    float acc[16];
#pragma unroll
    for (int i = 0; i < 16; ++i) acc[i] = 0.f;

    for (int ko = 0; ko < H_ / 8; ++ko) {
        float wv[8];
#pragma unroll
        for (int j = 0; j < 8; ++j) wv[j] = Wd[(ko * 8 + j) * N_ + n];
#pragma unroll
        for (int i = 0; i < 16; ++i) {
            int r = half * 16 + i;
            const uint4 hv = *(const uint4*)(sH + r * H_ + ko * 8);   // 8 bf16, LDS broadcast
            acc[i] += __uint_as_float(hv.x << 16) * wv[0] + __uint_as_float(hv.x & 0xFFFF0000u) * wv[1]
                    + __uint_as_float(hv.y << 16) * wv[2] + __uint_as_float(hv.y & 0xFFFF0000u) * wv[3]
                    + __uint_as_float(hv.z << 16) * wv[4] + __uint_as_float(hv.z & 0xFFFF0000u) * wv[5]
                    + __uint_as_float(hv.w << 16) * wv[6] + __uint_as_float(hv.w & 0xFFFF0000u) * wv[7];
        }
    }
    float sse = 0.f;
#pragma unroll
    for (int i = 0; i < 16; ++i) {
        int R = R0 + half * 16 + i;
        int t = R >> 6, b = R & 63;
        float logit = sigf(acc[i] + bdv);
        float d = Y[(size_t)(b * T_ + t) * N_ + n] - logit;
        sse += d * d;
    }
    for (int off = 32; off > 0; off >>= 1) sse += __shfl_down(sse, off, 64);
    if ((tid & 63) == 0) red[tid >> 6] = sse;
    __syncthreads();
    if (tid == 0) {
        float tot = red[0] + red[1] + red[2] + red[3];
        atomicAdd(out, tot * (100.0f / 4194304.0f));
    }
}

extern "C" void kernel_launch(void* const* d_in, const int* in_sizes, int n_in,
                              void* d_out, int out_size, void* d_ws, size_t ws_size,
                              hipStream_t stream) {
    (void)in_sizes; (void)n_in; (void)out_size;
    const float* X  = (const float*)d_in[0];
    const float* Y  = (const float*)d_in[1];
    const float* Wx = (const float*)d_in[2];
    const float* Wh = (const float*)d_in[3];
    const float* bb = (const float*)d_in[4];
    const float* Wd = (const float*)d_in[5];
    const float* bd = (const float*)d_in[6];

    char* ws = (char*)d_ws;
    u32* flags = (u32*)ws;                     // 64 flags x 128B = 8KB
    const size_t flag_bytes = 16384;
    u16* hs  = (u16*)(ws + flag_bytes);
    const size_t hs_bytes = (size_t)(T_ + 1) * 64 * H_ * 2;          // 33,619,968
    u16* Xb  = (u16*)(ws + flag_bytes + hs_bytes);
    const size_t xb_bytes = (size_t)T_ * 64 * N_ * 2;                // 8,388,608
    u16* Wt  = (u16*)(ws + flag_bytes + hs_bytes + xb_bytes);
    const size_t need = flag_bytes + hs_bytes + xb_bytes + (size_t)2048 * KDIM * 2;
    if (ws_size < need) return;   // ~44.7 MB scratch required

    (void)hipMemsetAsync(flags, 0, flag_bytes, stream);
    (void)hipMemsetAsync(hs, 0, 64 * H_ * 2, stream);      // h_{-1} = 0
    (void)hipMemsetAsync(d_out, 0, sizeof(float), stream);

    k_xb<<<dim3((B_ * T_ * N_) / 256), dim3(256), 0, stream>>>(X, Xb);
    k_wcat<<<dim3((2048 * KDIM) / 256), dim3(256), 0, stream>>>(Wx, Wh, Wt);

    void* args[] = { (void*)&Wt, (void*)&Xb, (void*)&hs, (void*)&bb, (void*)&flags };
    (void)hipLaunchCooperativeKernel((const void*)k_lstm, dim3(NWG), dim3(256), args, 0, stream);

    k_dec<<<dim3((B_ * T_) / 32), dim3(256), 0, stream>>>(hs, Wd, bd, Y, (float*)d_out);
}